// Round 4
// baseline (151.138 us; speedup 1.0000x reference)
//
#include <hip/hip_runtime.h>

#define NLOG2E -1.44269504088896340736f

// Algebra: u = (-c*log2e)*t computed directly via prefolded W1/b1.
//   sigma(c*t) = rcp(1 + exp2(u));  h_eff = u*sigma
//   real h = a1*t*sigma = h_eff * (a1 / (-c1*log2e))  -> folded into W2.
// Layer 2: t2 = sum h_eff*w2f + b2; u2 = (-c2*log2e)*t2;
//   out += (t2 * rcp(1+exp2(u2))) * (a2*W3)
// Stage-wise over 4 rows/thread: 32-wide independent chains per stage.

__global__ __launch_bounds__(256, 4) void PlaygroundModel_66365834658304_kernel(
    const float* __restrict__ x,
    const float* __restrict__ W1, const float* __restrict__ b1,
    const float* __restrict__ a1, const float* __restrict__ c1,
    const float* __restrict__ W2, const float* __restrict__ b2,
    const float* __restrict__ a2, const float* __restrict__ c2,
    const float* __restrict__ W3, const float* __restrict__ b3,
    float* __restrict__ out, int rows)
{
    int tid = blockIdx.x * blockDim.x + threadIdx.x;

    // ---- uniform prefold (~65 VGPRs of constants, ~70 uniform VALU ops) ----
    float uw0[8], uw1[8], ub[8], w2f[32];
#pragma unroll
    for (int j = 0; j < 8; ++j) {
        float ncl = c1[j] * NLOG2E;              // -c1*log2e
        uw0[j] = W1[j]     * ncl;
        uw1[j] = W1[8 + j] * ncl;
        ub[j]  = b1[j]     * ncl;
        float k1 = a1[j] * __builtin_amdgcn_rcpf(ncl);   // a1/(-c1*log2e)
#pragma unroll
        for (int k = 0; k < 4; ++k) w2f[j * 4 + k] = W2[j * 4 + k] * k1;
    }
    float ncl2[4], aw2[4];
#pragma unroll
    for (int k = 0; k < 4; ++k) {
        ncl2[k] = c2[k] * NLOG2E;
        aw2[k]  = a2[k] * W3[k];
    }
    float bb3 = b3[0];

    long long base = (long long)tid * 4;
    if (base + 3 < rows) {
        const float4* x4 = (const float4*)x;
        float4 p0 = x4[(size_t)tid * 2 + 0];
        float4 p1 = x4[(size_t)tid * 2 + 1];
        float X0[4] = {p0.x, p0.z, p1.x, p1.z};
        float X1[4] = {p0.y, p0.w, p1.y, p1.w};

        // stage 1: all 32 u-values (independent fma pairs)
        float u[4][8];
#pragma unroll
        for (int r = 0; r < 4; ++r)
#pragma unroll
            for (int j = 0; j < 8; ++j)
                u[r][j] = fmaf(X0[r], uw0[j], fmaf(X1[r], uw1[j], ub[j]));

        // stage 2: 32 independent exp2 / add / rcp / mul chains
#pragma unroll
        for (int r = 0; r < 4; ++r)
#pragma unroll
            for (int j = 0; j < 8; ++j) {
                float e = __builtin_amdgcn_exp2f(u[r][j]);
                float s = __builtin_amdgcn_rcpf(1.0f + e);
                u[r][j] = u[r][j] * s;           // h_eff, in place
            }

        // stage 3: layer-2 GEMV (16 independent dot-8), then 16 activations
        float t2[4][4];
#pragma unroll
        for (int r = 0; r < 4; ++r)
#pragma unroll
            for (int k = 0; k < 4; ++k) {
                float t = b2[k];
#pragma unroll
                for (int j = 0; j < 8; ++j)
                    t = fmaf(u[r][j], w2f[j * 4 + k], t);
                t2[r][k] = t;
            }

        float res[4];
#pragma unroll
        for (int r = 0; r < 4; ++r) {
            float o = bb3;
#pragma unroll
            for (int k = 0; k < 4; ++k) {
                float u2 = ncl2[k] * t2[r][k];
                float s2 = __builtin_amdgcn_rcpf(
                               1.0f + __builtin_amdgcn_exp2f(u2));
                o = fmaf(t2[r][k] * s2, aw2[k], o);
            }
            res[r] = o;
        }
        ((float4*)out)[tid] = make_float4(res[0], res[1], res[2], res[3]);
    } else if (base < rows) {
        // tail (not hit for B = 8388608)
        for (long long rr = base; rr < rows; ++rr) {
            float x0 = x[rr * 2 + 0], x1 = x[rr * 2 + 1];
            float o = bb3;
            float h[8];
#pragma unroll
            for (int j = 0; j < 8; ++j) {
                float uu = fmaf(x0, uw0[j], fmaf(x1, uw1[j], ub[j]));
                float s  = __builtin_amdgcn_rcpf(
                               1.0f + __builtin_amdgcn_exp2f(uu));
                h[j] = uu * s;
            }
#pragma unroll
            for (int k = 0; k < 4; ++k) {
                float t = b2[k];
#pragma unroll
                for (int j = 0; j < 8; ++j) t = fmaf(h[j], w2f[j * 4 + k], t);
                float u2 = ncl2[k] * t;
                float s2 = __builtin_amdgcn_rcpf(
                               1.0f + __builtin_amdgcn_exp2f(u2));
                o = fmaf(t * s2, aw2[k], o);
            }
            out[rr] = o;
        }
    }
}

extern "C" void kernel_launch(void* const* d_in, const int* in_sizes, int n_in,
                              void* d_out, int out_size, void* d_ws, size_t ws_size,
                              hipStream_t stream) {
    const float* x  = (const float*)d_in[0];
    const float* W1 = (const float*)d_in[1];
    const float* b1 = (const float*)d_in[2];
    const float* a1 = (const float*)d_in[3];
    const float* c1 = (const float*)d_in[4];
    const float* W2 = (const float*)d_in[5];
    const float* b2 = (const float*)d_in[6];
    const float* a2 = (const float*)d_in[7];
    const float* c2 = (const float*)d_in[8];
    const float* W3 = (const float*)d_in[9];
    const float* b3 = (const float*)d_in[10];
    float* out = (float*)d_out;

    int rows  = in_sizes[0] / 2;
    int rows4 = (rows + 3) / 4;            // 4 rows per thread
    int block = 256;
    int grid  = (rows4 + block - 1) / block;

    PlaygroundModel_66365834658304_kernel<<<grid, block, 0, stream>>>(
        x, W1, b1, a1, c1, W2, b2, a2, c2, W3, b3, out, rows);
}

// Round 5
// 126.647 us; speedup vs baseline: 1.1934x; 1.1934x over previous
//
#include <hip/hip_runtime.h>

#define NLOG2E -1.44269504088896340736f

// Two-kernel scheme:
//   K1 (1 thread): fold all weight algebra into 69 floats in d_ws.
//   K2: per-row MLP; reads folded constants via uniform pointer -> s_load ->
//       SGPRs (zero VGPR cost, no per-thread fold math, no spill).
//
// Algebra: u = (-c1*log2e)*t1 directly from prefolded W1/b1.
//   sigma = rcp(1+exp2(u)); h_eff = u*sigma;
//   real h = h_eff * (a1/(-c1*log2e))  -> folded into W2.
//   layer2: t2 = h_eff@w2f + b2; out += (t2*rcp(1+exp2(ncl2*t2)))*(a2*W3) + b3
//
// ws layout (floats): [0:8)=uw0 [8:16)=uw1 [16:24)=ub [24:56)=w2f
//                     [56:60)=b2 [60:64)=ncl2 [64:68)=aw2 [68]=bb3

__global__ void prefold_kernel(
    const float* __restrict__ W1, const float* __restrict__ b1,
    const float* __restrict__ a1, const float* __restrict__ c1,
    const float* __restrict__ W2, const float* __restrict__ b2,
    const float* __restrict__ a2, const float* __restrict__ c2,
    const float* __restrict__ W3, const float* __restrict__ b3,
    float* __restrict__ C)
{
    if (threadIdx.x == 0 && blockIdx.x == 0) {
        for (int j = 0; j < 8; ++j) {
            float ncl = c1[j] * NLOG2E;
            C[j]      = W1[j]     * ncl;
            C[8 + j]  = W1[8 + j] * ncl;
            C[16 + j] = b1[j]     * ncl;
            float k1 = a1[j] / ncl;            // exact divide, runs once
            for (int k = 0; k < 4; ++k)
                C[24 + j * 4 + k] = W2[j * 4 + k] * k1;
        }
        for (int k = 0; k < 4; ++k) {
            C[56 + k] = b2[k];
            C[60 + k] = c2[k] * NLOG2E;
            C[64 + k] = a2[k] * W3[k];
        }
        C[68] = b3[0];
    }
}

__global__ __launch_bounds__(256, 4) void PlaygroundModel_66365834658304_kernel(
    const float* __restrict__ x, const float* __restrict__ C,
    float* __restrict__ out, int rows)
{
    int tid = blockIdx.x * blockDim.x + threadIdx.x;
    long long base = (long long)tid * 4;

    const float* uw0  = C;        // 8
    const float* uw1  = C + 8;    // 8
    const float* ub   = C + 16;   // 8
    const float* w2f  = C + 24;   // 32
    const float* bb2  = C + 56;   // 4
    const float* ncl2 = C + 60;   // 4
    const float* aw2  = C + 64;   // 4
    float bb3 = C[68];

    if (base + 3 < rows) {
        const float4* x4 = (const float4*)x;
        float4 p0 = x4[(size_t)tid * 2 + 0];
        float4 p1 = x4[(size_t)tid * 2 + 1];
        float X0[4] = {p0.x, p0.z, p1.x, p1.z};
        float X1[4] = {p0.y, p0.w, p1.y, p1.w};

        // stage 1: 32 independent u-values (fma pairs)
        float u[4][8];
#pragma unroll
        for (int r = 0; r < 4; ++r)
#pragma unroll
            for (int j = 0; j < 8; ++j)
                u[r][j] = fmaf(X0[r], uw0[j], fmaf(X1[r], uw1[j], ub[j]));

        // stage 2: 32 independent exp2/add/rcp/mul chains (latency pipelines)
#pragma unroll
        for (int r = 0; r < 4; ++r)
#pragma unroll
            for (int j = 0; j < 8; ++j) {
                float e = __builtin_amdgcn_exp2f(u[r][j]);
                float s = __builtin_amdgcn_rcpf(1.0f + e);
                u[r][j] = u[r][j] * s;           // h_eff in place
            }

        // stage 3: 16 independent dot-8
        float t2[4][4];
#pragma unroll
        for (int r = 0; r < 4; ++r)
#pragma unroll
            for (int k = 0; k < 4; ++k) {
                float t = bb2[k];
#pragma unroll
                for (int j = 0; j < 8; ++j)
                    t = fmaf(u[r][j], w2f[j * 4 + k], t);
                t2[r][k] = t;
            }

        // stage 4: 16 independent activation chains, then reduce
        float s2[4][4];
#pragma unroll
        for (int r = 0; r < 4; ++r)
#pragma unroll
            for (int k = 0; k < 4; ++k) {
                float u2 = ncl2[k] * t2[r][k];
                s2[r][k] = __builtin_amdgcn_rcpf(
                               1.0f + __builtin_amdgcn_exp2f(u2));
            }
        float res[4];
#pragma unroll
        for (int r = 0; r < 4; ++r) {
            float o = bb3;
#pragma unroll
            for (int k = 0; k < 4; ++k)
                o = fmaf(t2[r][k] * s2[r][k], aw2[k], o);
            res[r] = o;
        }
        ((float4*)out)[tid] = make_float4(res[0], res[1], res[2], res[3]);
    } else if (base < rows) {
        // tail (not hit for B = 8388608)
        for (long long rr = base; rr < rows; ++rr) {
            float x0 = x[rr * 2 + 0], x1 = x[rr * 2 + 1];
            float o = bb3;
            float h[8];
#pragma unroll
            for (int j = 0; j < 8; ++j) {
                float uu = fmaf(x0, uw0[j], fmaf(x1, uw1[j], ub[j]));
                float s  = __builtin_amdgcn_rcpf(
                               1.0f + __builtin_amdgcn_exp2f(uu));
                h[j] = uu * s;
            }
#pragma unroll
            for (int k = 0; k < 4; ++k) {
                float t = bb2[k];
#pragma unroll
                for (int j = 0; j < 8; ++j) t = fmaf(h[j], w2f[j * 4 + k], t);
                float u2 = ncl2[k] * t;
                float sg = __builtin_amdgcn_rcpf(
                               1.0f + __builtin_amdgcn_exp2f(u2));
                o = fmaf(t * sg, aw2[k], o);
            }
            out[rr] = o;
        }
    }
}

extern "C" void kernel_launch(void* const* d_in, const int* in_sizes, int n_in,
                              void* d_out, int out_size, void* d_ws, size_t ws_size,
                              hipStream_t stream) {
    const float* x  = (const float*)d_in[0];
    const float* W1 = (const float*)d_in[1];
    const float* b1 = (const float*)d_in[2];
    const float* a1 = (const float*)d_in[3];
    const float* c1 = (const float*)d_in[4];
    const float* W2 = (const float*)d_in[5];
    const float* b2 = (const float*)d_in[6];
    const float* a2 = (const float*)d_in[7];
    const float* c2 = (const float*)d_in[8];
    const float* W3 = (const float*)d_in[9];
    const float* b3 = (const float*)d_in[10];
    float* out = (float*)d_out;
    float* C   = (float*)d_ws;             // 69 floats of folded constants

    prefold_kernel<<<1, 64, 0, stream>>>(W1, b1, a1, c1, W2, b2, a2, c2,
                                         W3, b3, C);

    int rows  = in_sizes[0] / 2;
    int rows4 = (rows + 3) / 4;            // 4 rows per thread
    int block = 256;
    int grid  = (rows4 + block - 1) / block;

    PlaygroundModel_66365834658304_kernel<<<grid, block, 0, stream>>>(
        x, C, out, rows);
}